// Round 2
// baseline (712.514 us; speedup 1.0000x reference)
//
#include <hip/hip_runtime.h>

typedef unsigned short u16;
typedef __bf16 bf16_t;
typedef bf16_t bf16x8 __attribute__((ext_vector_type(8)));
typedef float f32x4 __attribute__((ext_vector_type(4)));
typedef u16 u16x8 __attribute__((ext_vector_type(8)));

#define T_SZ 2048
#define EMB 1024

static __device__ __forceinline__ u16 f2bf(float f) {
  union { float f; unsigned u; } v; v.f = f;
  return (u16)((v.u + 0x7fffu + ((v.u >> 16) & 1u)) >> 16);  // RNE
}
static __device__ __forceinline__ void async16(const u16* g, u16* l) {
  typedef const __attribute__((address_space(1))) unsigned int* gp_t;
  typedef __attribute__((address_space(3))) unsigned int* lp_t;
  // LDS dest is wave-uniform base + lane*16B; callers pass the wave-uniform base.
  __builtin_amdgcn_global_load_lds((gp_t)(const void*)g, (lp_t)(void*)l, 16, 0, 0);
}

// fp32 -> bf16 (RNE), 8 elems/thread. n must be handled with the guard.
__global__ __launch_bounds__(256) void f32_to_bf16(
    const float* __restrict__ src, u16* __restrict__ dst, int n) {
  int i = (blockIdx.x * 256 + threadIdx.x) * 8;
  if (i >= n) return;
  float4 a = *(const float4*)(src + i);
  float4 b = *(const float4*)(src + i + 4);
  u16x8 o;
  o[0] = f2bf(a.x); o[1] = f2bf(a.y); o[2] = f2bf(a.z); o[3] = f2bf(a.w);
  o[4] = f2bf(b.x); o[5] = f2bf(b.y); o[6] = f2bf(b.z); o[7] = f2bf(b.w);
  *(u16x8*)(dst + i) = o;
}

// C[m][n] = sum_k A[m][k] * Bm[n][k] (+ bias[n]).  bf16 in, fp32 accum,
// out bf16 (to ws) or fp32 (to d_out). 128x128 tile, BK=64, 4 waves (2x2 of 64x64).
template <bool OUT_F32>
__global__ __launch_bounds__(256, 2) void gemm_bt(
    const u16* __restrict__ A, const u16* __restrict__ Bm,
    const float* __restrict__ bias, void* __restrict__ Cv,
    int M, int N, int K) {
  __shared__ u16 as[128 * 64];
  __shared__ u16 bs[128 * 64];
  const int tid = threadIdx.x;
  const int lane = tid & 63, wv = tid >> 6;
  const int quad = lane >> 4, l16 = lane & 15;
  const int tm = blockIdx.x * 128, tn = blockIdx.y * 128;
  const int wm = (wv & 1) * 64, wn = (wv >> 1) * 64;
  const int rA = lane >> 3, cA = (lane & 7) * 8;  // 8 rows x 8 chunks per wave-load
  f32x4 acc[4][4] = {};
  for (int k0 = 0; k0 < K; k0 += 64) {
#pragma unroll
    for (int it = 0; it < 4; ++it) {
      int r0 = it * 32 + wv * 8;  // wave-uniform LDS base row
      async16(A + (size_t)(tm + r0 + rA) * K + k0 + cA, &as[r0 * 64]);
      async16(Bm + (size_t)(tn + r0 + rA) * K + k0 + cA, &bs[r0 * 64]);
    }
    __syncthreads();  // drains vmcnt for global_load_lds
#pragma unroll
    for (int kk = 0; kk < 64; kk += 32) {
      bf16x8 af[4], bfr[4];
#pragma unroll
      for (int i = 0; i < 4; ++i)
        af[i] = *(const bf16x8*)&as[(wm + i * 16 + l16) * 64 + kk + quad * 8];
#pragma unroll
      for (int j = 0; j < 4; ++j)
        bfr[j] = *(const bf16x8*)&bs[(wn + j * 16 + l16) * 64 + kk + quad * 8];
#pragma unroll
      for (int i = 0; i < 4; ++i)
#pragma unroll
        for (int j = 0; j < 4; ++j)
          acc[i][j] = __builtin_amdgcn_mfma_f32_16x16x32_bf16(af[i], bfr[j], acc[i][j], 0, 0, 0);
    }
    __syncthreads();
  }
  // Epilogue: C/D layout col(n)=lane&15, row(m)=quad*4+reg (verified m89/m91).
#pragma unroll
  for (int i = 0; i < 4; ++i)
#pragma unroll
    for (int j = 0; j < 4; ++j) {
      int col = tn + wn + j * 16 + l16;
      float bv = bias ? bias[col] : 0.0f;
#pragma unroll
      for (int r = 0; r < 4; ++r) {
        int row = tm + wm + i * 16 + quad * 4 + r;
        if (OUT_F32)
          ((float*)Cv)[(size_t)row * N + col] = acc[i][j][r] + bv;
        else
          ((u16*)Cv)[(size_t)row * N + col] = f2bf(acc[i][j][r] + bv);
      }
    }
}

// Flash attention, causal, GQA. Q:[B*T,1024] (h*64+d), K/V:[B*T,256] (g*64+d).
// Block = (qb 64 rows, h, b); 4 waves each own a 16-row q strip. K-tile = 64.
__global__ __launch_bounds__(256, 2) void gqa_attn(
    const u16* __restrict__ Q, const u16* __restrict__ Kg,
    const u16* __restrict__ Vg, u16* __restrict__ O) {
  __shared__ u16 kls[64 * 64];      // K-tile [kpos][d]
  __shared__ u16 vtls[64 * 64];     // V-tile transposed [d][kpos]
  __shared__ u16 pls[4][16 * 64];   // per-wave P [q][kpos]
  const int tid = threadIdx.x;
  const int lane = tid & 63, wv = tid >> 6;
  const int quad = lane >> 4, l16 = lane & 15;
  const int qb = blockIdx.x, h = blockIdx.y, b = blockIdx.z;
  const int g = h >> 2;  // GROUP_SIZE = 4
  const size_t bT = (size_t)b * T_SZ;
  const int qstrip = qb * 64 + wv * 16;

  // Q fragments (A-operand layout: m=lane&15, k=quad*8+j), held for the whole loop.
  const u16* qp = Q + (bT + qstrip + l16) * EMB + h * 64 + quad * 8;
  const bf16x8 qf0 = *(const bf16x8*)qp;
  const bf16x8 qf1 = *(const bf16x8*)(qp + 32);

  f32x4 o[4] = {};            // O accum [q=quad*4+r][d=j*16+l16]
  float mrow[4], lrow[4];
#pragma unroll
  for (int r = 0; r < 4; ++r) { mrow[r] = -1e30f; lrow[r] = 0.0f; }

  for (int kt = 0; kt <= qb; ++kt) {
    const int kbase = kt * 64;
    // Stage K (async, row-major [kpos][64])
#pragma unroll
    for (int it = 0; it < 2; ++it) {
      int r0 = it * 32 + wv * 8;
      async16(Kg + (bT + kbase + r0 + (lane >> 3)) * 256 + g * 64 + (lane & 7) * 8,
              &kls[r0 * 64]);
    }
    // Stage V transposed (regular writes): vtls[d][kpos]
#pragma unroll
    for (int p = 0; p < 4; ++p) {
      int e = (p * 256 + tid) * 4;
      int kp = e >> 6, d0 = e & 63;
      ushort4 v4 = *(const ushort4*)(Vg + (bT + kbase + kp) * 256 + g * 64 + d0);
      vtls[(d0 + 0) * 64 + kp] = v4.x;
      vtls[(d0 + 1) * 64 + kp] = v4.y;
      vtls[(d0 + 2) * 64 + kp] = v4.z;
      vtls[(d0 + 3) * 64 + kp] = v4.w;
    }
    __syncthreads();

    // S = Q K^T  (16 q x 64 k per wave)
    f32x4 s[4];
#pragma unroll
    for (int jn = 0; jn < 4; ++jn) {
      bf16x8 kf0 = *(const bf16x8*)&kls[(jn * 16 + l16) * 64 + quad * 8];
      bf16x8 kf1 = *(const bf16x8*)&kls[(jn * 16 + l16) * 64 + 32 + quad * 8];
      f32x4 a = {};
      a = __builtin_amdgcn_mfma_f32_16x16x32_bf16(qf0, kf0, a, 0, 0, 0);
      a = __builtin_amdgcn_mfma_f32_16x16x32_bf16(qf1, kf1, a, 0, 0, 0);
      s[jn] = a;
    }
    const bool diag = (kt == qb);
#pragma unroll
    for (int jn = 0; jn < 4; ++jn)
#pragma unroll
      for (int r = 0; r < 4; ++r) {
        float v = s[jn][r] * 0.125f;  // HEAD_DIM^-0.5
        if (diag && (jn * 16 + l16 > wv * 16 + quad * 4 + r)) v = -1e30f;
        s[jn][r] = v;
      }

    // Online softmax (row = quad*4+r spans the quad's 16 lanes)
    float pm[4][4], al[4];
#pragma unroll
    for (int r = 0; r < 4; ++r) {
      float v = fmaxf(fmaxf(s[0][r], s[1][r]), fmaxf(s[2][r], s[3][r]));
#pragma unroll
      for (int off = 1; off < 16; off <<= 1) v = fmaxf(v, __shfl_xor(v, off, 16));
      float mnew = fmaxf(mrow[r], v);
      al[r] = expf(mrow[r] - mnew);
      float sum = 0.0f;
#pragma unroll
      for (int jn = 0; jn < 4; ++jn) { pm[jn][r] = expf(s[jn][r] - mnew); sum += pm[jn][r]; }
#pragma unroll
      for (int off = 1; off < 16; off <<= 1) sum += __shfl_xor(sum, off, 16);
      lrow[r] = lrow[r] * al[r] + sum;
      mrow[r] = mnew;
    }
    // P: C-layout -> LDS -> A-layout (m120 pattern); rescale O.
#pragma unroll
    for (int jn = 0; jn < 4; ++jn)
#pragma unroll
      for (int r = 0; r < 4; ++r)
        pls[wv][(quad * 4 + r) * 64 + jn * 16 + l16] = f2bf(pm[jn][r]);
#pragma unroll
    for (int j = 0; j < 4; ++j)
#pragma unroll
      for (int r = 0; r < 4; ++r) o[j][r] *= al[r];
    // Full barrier: true compiler+HW memory fence for the u16-store -> bf16x8-load
    // round-trip (wave_barrier is IntrNoMem; TBAA could hoist the typed load).
    __syncthreads();
    bf16x8 pf0 = *(const bf16x8*)&pls[wv][l16 * 64 + quad * 8];
    bf16x8 pf1 = *(const bf16x8*)&pls[wv][l16 * 64 + 32 + quad * 8];
#pragma unroll
    for (int j = 0; j < 4; ++j) {
      bf16x8 vf0 = *(const bf16x8*)&vtls[(j * 16 + l16) * 64 + quad * 8];
      bf16x8 vf1 = *(const bf16x8*)&vtls[(j * 16 + l16) * 64 + 32 + quad * 8];
      o[j] = __builtin_amdgcn_mfma_f32_16x16x32_bf16(pf0, vf0, o[j], 0, 0, 0);
      o[j] = __builtin_amdgcn_mfma_f32_16x16x32_bf16(pf1, vf1, o[j], 0, 0, 0);
    }
    __syncthreads();
  }
  // Normalize + write O[b*T+q][h*64+d]
#pragma unroll
  for (int r = 0; r < 4; ++r) {
    float inv = 1.0f / lrow[r];
    int row = qstrip + quad * 4 + r;
#pragma unroll
    for (int j = 0; j < 4; ++j)
      O[(bT + row) * EMB + h * 64 + j * 16 + l16] = f2bf(o[j][r] * inv);
  }
}

extern "C" void kernel_launch(void* const* d_in, const int* in_sizes, int n_in,
                              void* d_out, int out_size, void* d_ws, size_t ws_size,
                              hipStream_t stream) {
  const float* x  = (const float*)d_in[0];  // [8192,1024] fp32
  const float* Wq = (const float*)d_in[1];  // [1024,1024] rows h*64+d
  const float* Wk = (const float*)d_in[2];  // [256,1024]  rows g*64+d
  const float* Wv = (const float*)d_in[3];  // [256,1024]
  const float* Wp = (const float*)d_in[4];  // [1024,1024]
  const float* bp = (const float*)d_in[5];  // [1024] fp32, used directly
  float* out = (float*)d_out;               // [8192,1024] fp32

  u16* ws = (u16*)d_ws;
  u16* Qb  = ws;                              // 8M u16
  u16* Kb  = Qb + (size_t)8192 * 1024;        // 2M
  u16* Vb  = Kb + (size_t)8192 * 256;         // 2M
  u16* xb  = Vb + (size_t)8192 * 256;         // 8M (reused as Ab after QKV)
  u16* Wqb = xb + (size_t)8192 * 1024;        // 1M
  u16* Wkb = Wqb + (size_t)1024 * 1024;       // 256K
  u16* Wvb = Wkb + (size_t)256 * 1024;        // 256K
  u16* Wpb = Wvb + (size_t)256 * 1024;        // 1M   -> total 22.5M u16 = 45 MB
  u16* Ab  = xb;                              // alias: x dead after QKV GEMMs

  f32_to_bf16<<<dim3(8192 * 1024 / 2048), 256, 0, stream>>>(x,  xb,  8192 * 1024);
  f32_to_bf16<<<dim3(1024 * 1024 / 2048), 256, 0, stream>>>(Wq, Wqb, 1024 * 1024);
  f32_to_bf16<<<dim3(256 * 1024 / 2048),  256, 0, stream>>>(Wk, Wkb, 256 * 1024);
  f32_to_bf16<<<dim3(256 * 1024 / 2048),  256, 0, stream>>>(Wv, Wvb, 256 * 1024);
  f32_to_bf16<<<dim3(1024 * 1024 / 2048), 256, 0, stream>>>(Wp, Wpb, 1024 * 1024);

  gemm_bt<false><<<dim3(64, 8), 256, 0, stream>>>(xb, Wqb, nullptr, Qb, 8192, 1024, 1024);
  gemm_bt<false><<<dim3(64, 2), 256, 0, stream>>>(xb, Wkb, nullptr, Kb, 8192, 256, 1024);
  gemm_bt<false><<<dim3(64, 2), 256, 0, stream>>>(xb, Wvb, nullptr, Vb, 8192, 256, 1024);

  gqa_attn<<<dim3(32, 16, 4), 256, 0, stream>>>(Qb, Kb, Vb, Ab);

  gemm_bt<true><<<dim3(64, 8), 256, 0, stream>>>(Ab, Wpb, bp, out, 8192, 1024, 1024);
}

// Round 3
// 425.662 us; speedup vs baseline: 1.6739x; 1.6739x over previous
//
#include <hip/hip_runtime.h>

typedef unsigned short u16;
typedef __bf16 bf16_t;
typedef bf16_t bf16x8 __attribute__((ext_vector_type(8)));
typedef float f32x4 __attribute__((ext_vector_type(4)));
typedef u16 u16x8 __attribute__((ext_vector_type(8)));

#define T_SZ 2048
#define EMB 1024

static __device__ __forceinline__ u16 f2bf(float f) {
  union { float f; unsigned u; } v; v.f = f;
  return (u16)((v.u + 0x7fffu + ((v.u >> 16) & 1u)) >> 16);  // RNE
}
static __device__ __forceinline__ void async16(const u16* g, u16* l) {
  typedef const __attribute__((address_space(1))) unsigned int* gp_t;
  typedef __attribute__((address_space(3))) unsigned int* lp_t;
  // LDS dest is wave-uniform base; HW scatters lane i to base + i*16B.
  __builtin_amdgcn_global_load_lds((gp_t)(const void*)g, (lp_t)(void*)l, 16, 0, 0);
}

// fp32 -> bf16 (RNE), 8 elems/thread.
__global__ __launch_bounds__(256) void f32_to_bf16(
    const float* __restrict__ src, u16* __restrict__ dst, int n) {
  int i = (blockIdx.x * 256 + threadIdx.x) * 8;
  if (i >= n) return;
  float4 a = *(const float4*)(src + i);
  float4 b = *(const float4*)(src + i + 4);
  u16x8 o;
  o[0] = f2bf(a.x); o[1] = f2bf(a.y); o[2] = f2bf(a.z); o[3] = f2bf(a.w);
  o[4] = f2bf(b.x); o[5] = f2bf(b.y); o[6] = f2bf(b.z); o[7] = f2bf(b.w);
  *(u16x8*)(dst + i) = o;
}

// V [b*T][g*64+d] -> Vt [(b*4+g)*64+d][T].  64x64 tiles via padded LDS.
__global__ __launch_bounds__(256) void transpose_v(
    const u16* __restrict__ V, u16* __restrict__ Vt) {
  __shared__ u16 tile[64][72];
  const int tt = blockIdx.x, g = blockIdx.y, b = blockIdx.z;
  const int tid = threadIdx.x;
  {
    const int r = tid >> 2, c = (tid & 3) * 16;
    const u16* src = V + ((size_t)(b * T_SZ + tt * 64 + r)) * 256 + g * 64 + c;
    *(u16x8*)&tile[r][c] = *(const u16x8*)src;
    *(u16x8*)&tile[r][c + 8] = *(const u16x8*)(src + 8);
  }
  __syncthreads();
  {
    const int d = tid >> 2, t0 = (tid & 3) * 16;
    u16x8 o0, o1;
#pragma unroll
    for (int i = 0; i < 8; ++i) { o0[i] = tile[t0 + i][d]; o1[i] = tile[t0 + 8 + i][d]; }
    u16* dst = Vt + ((size_t)((b * 4 + g) * 64 + d)) * T_SZ + tt * 64 + t0;
    *(u16x8*)dst = o0;
    *(u16x8*)(dst + 8) = o1;
  }
}

// C[m][n] = sum_k A[m][k] * Bm[n][k] (+ bias[n]).  bf16 in, fp32 accum,
// out bf16 (ws) or fp32 (d_out). 128x128 tile, BK=64, 4 waves (2x2 of 64x64).
template <bool OUT_F32>
__global__ __launch_bounds__(256, 2) void gemm_bt(
    const u16* __restrict__ A, const u16* __restrict__ Bm,
    const float* __restrict__ bias, void* __restrict__ Cv,
    int M, int N, int K) {
  __shared__ u16 as[128 * 64];
  __shared__ u16 bs[128 * 64];
  const int tid = threadIdx.x;
  const int lane = tid & 63, wv = tid >> 6;
  const int quad = lane >> 4, l16 = lane & 15;
  const int tm = blockIdx.x * 128, tn = blockIdx.y * 128;
  const int wm = (wv & 1) * 64, wn = (wv >> 1) * 64;
  const int rA = lane >> 3, cA = (lane & 7) * 8;
  f32x4 acc[4][4] = {};
  for (int k0 = 0; k0 < K; k0 += 64) {
#pragma unroll
    for (int it = 0; it < 4; ++it) {
      int r0 = it * 32 + wv * 8;
      async16(A + (size_t)(tm + r0 + rA) * K + k0 + cA, &as[r0 * 64]);
      async16(Bm + (size_t)(tn + r0 + rA) * K + k0 + cA, &bs[r0 * 64]);
    }
    __syncthreads();
#pragma unroll
    for (int kk = 0; kk < 64; kk += 32) {
      bf16x8 af[4], bfr[4];
#pragma unroll
      for (int i = 0; i < 4; ++i)
        af[i] = *(const bf16x8*)&as[(wm + i * 16 + l16) * 64 + kk + quad * 8];
#pragma unroll
      for (int j = 0; j < 4; ++j)
        bfr[j] = *(const bf16x8*)&bs[(wn + j * 16 + l16) * 64 + kk + quad * 8];
#pragma unroll
      for (int i = 0; i < 4; ++i)
#pragma unroll
        for (int j = 0; j < 4; ++j)
          acc[i][j] = __builtin_amdgcn_mfma_f32_16x16x32_bf16(af[i], bfr[j], acc[i][j], 0, 0, 0);
    }
    __syncthreads();
  }
#pragma unroll
  for (int i = 0; i < 4; ++i)
#pragma unroll
    for (int j = 0; j < 4; ++j) {
      int col = tn + wn + j * 16 + l16;
      float bv = bias ? bias[col] : 0.0f;
#pragma unroll
      for (int r = 0; r < 4; ++r) {
        int row = tm + wm + i * 16 + quad * 4 + r;
        if (OUT_F32)
          ((float*)Cv)[(size_t)row * N + col] = acc[i][j][r] + bv;
        else
          ((u16*)Cv)[(size_t)row * N + col] = f2bf(acc[i][j][r] + bv);
      }
    }
}

// Flash attention, causal, GQA.  Q:[B*T][1024] (h*64+d), K:[B*T][256] (g*64+d),
// Vt:[(b*4+g)*64+d][T].  Block = (qb, h, b); wave wv owns q rows qb*64+wv*16..+15.
// S^T via mfma(A=K, B=Q): per-lane rows q=l16 -> 2-shuffle softmax, b64 P stores.
// Double-buffered K/V staging; prefetch issued after the single barrier.
__global__ __launch_bounds__(256, 3) void gqa_attn(
    const u16* __restrict__ Q, const u16* __restrict__ Kg,
    const u16* __restrict__ Vt, u16* __restrict__ O) {
  __shared__ u16 kbuf[2][64 * 64];   // K-tile [kpos][d]
  __shared__ u16 vbuf[2][64 * 64];   // V^T-tile [d][kpos]
  __shared__ u16 pls[4][16 * 72];    // per-wave P [q][kpos], stride 72 (bank pad)
  const int tid = threadIdx.x;
  const int lane = tid & 63, wv = tid >> 6;
  const int quad = lane >> 4, l16 = lane & 15;
  const int qb = (int)(gridDim.x - 1) - (int)blockIdx.x;  // longest blocks first
  const int h = blockIdx.y, b = blockIdx.z;
  const int g = h >> 2;
  const size_t bT = (size_t)b * T_SZ;
  const int qstrip = qb * 64 + wv * 16;
  const int rA = lane >> 3, cA = (lane & 7) * 8;
  const u16* vtb = Vt + (size_t)((b * 4 + g) * 64) * T_SZ;

  // Q fragment (lane: q=l16, d=quad*8+j), reused for all kt.
  const u16* qp = Q + (bT + qstrip + l16) * EMB + h * 64 + quad * 8;
  const bf16x8 qf0 = *(const bf16x8*)qp;
  const bf16x8 qf1 = *(const bf16x8*)(qp + 32);

  f32x4 o[4] = {};           // O^C: [q=quad*4+r][d=j*16+l16]
  float m_l = -1e30f, l_l = 0.0f;  // per-lane running max/sum for q = qstrip+l16
  const float SCALE2 = 0.18033688011112042f;  // 0.125 * log2(e)

#define STAGE(KT, BUF)                                                              \
  do {                                                                              \
    int kb_ = (KT) * 64, r0_ = wv * 16;                                             \
    async16(Kg + (bT + kb_ + r0_ + rA) * 256 + g * 64 + cA, &kbuf[BUF][r0_ * 64]);  \
    async16(Kg + (bT + kb_ + r0_ + 8 + rA) * 256 + g * 64 + cA,                     \
            &kbuf[BUF][(r0_ + 8) * 64]);                                            \
    async16(vtb + (size_t)(r0_ + rA) * T_SZ + kb_ + cA, &vbuf[BUF][r0_ * 64]);      \
    async16(vtb + (size_t)(r0_ + 8 + rA) * T_SZ + kb_ + cA,                         \
            &vbuf[BUF][(r0_ + 8) * 64]);                                            \
  } while (0)

  STAGE(0, 0);
  for (int kt = 0; kt <= qb; ++kt) {
    const int cur = kt & 1;
    __syncthreads();                 // drains stage(kt) (prefetched a full iter ago)
    if (kt < qb) STAGE(kt + 1, cur ^ 1);

    // S^T = K Q^T : s[jn][r] = S[kpos = kt*64 + jn*16 + quad*4 + r][q = qstrip+l16]
    f32x4 s[4];
#pragma unroll
    for (int jn = 0; jn < 4; ++jn) {
      bf16x8 kf0 = *(const bf16x8*)&kbuf[cur][(jn * 16 + l16) * 64 + quad * 8];
      bf16x8 kf1 = *(const bf16x8*)&kbuf[cur][(jn * 16 + l16) * 64 + 32 + quad * 8];
      f32x4 a = {};
      a = __builtin_amdgcn_mfma_f32_16x16x32_bf16(kf0, qf0, a, 0, 0, 0);
      a = __builtin_amdgcn_mfma_f32_16x16x32_bf16(kf1, qf1, a, 0, 0, 0);
      s[jn] = a;
    }
    const int qg = qstrip + l16, kb = kt * 64;
#pragma unroll
    for (int jn = 0; jn < 4; ++jn)
#pragma unroll
      for (int r = 0; r < 4; ++r) {
        float v = s[jn][r] * SCALE2;               // log2 domain
        if (kb + jn * 16 + quad * 4 + r > qg) v = -1e30f;
        s[jn][r] = v;
      }

    // Online softmax: one q-row per lane. Intra-lane 16-max, then xor16/xor32.
    float mx = -1e30f;
#pragma unroll
    for (int jn = 0; jn < 4; ++jn)
#pragma unroll
      for (int r = 0; r < 4; ++r) mx = fmaxf(mx, s[jn][r]);
    mx = fmaxf(mx, __shfl_xor(mx, 16));
    mx = fmaxf(mx, __shfl_xor(mx, 32));
    float mnew = fmaxf(m_l, mx);
    float alpha = exp2f(m_l - mnew);
    float sum = 0.0f;
#pragma unroll
    for (int jn = 0; jn < 4; ++jn)
#pragma unroll
      for (int r = 0; r < 4; ++r) { s[jn][r] = exp2f(s[jn][r] - mnew); sum += s[jn][r]; }
    sum += __shfl_xor(sum, 16);
    sum += __shfl_xor(sum, 32);
    l_l = l_l * alpha + sum;
    m_l = mnew;

    // P store: 4 consecutive kpos per lane -> ds_write_b64 into padded rows.
#pragma unroll
    for (int jn = 0; jn < 4; ++jn) {
      ushort4 pk;
      pk.x = f2bf(s[jn][0]); pk.y = f2bf(s[jn][1]);
      pk.z = f2bf(s[jn][2]); pk.w = f2bf(s[jn][3]);
      *(ushort4*)&pls[wv][l16 * 72 + jn * 16 + quad * 4] = pk;
    }
    // Rescale O by alpha[row q = quad*4+r] (fetched cross-lane).
#pragma unroll
    for (int r = 0; r < 4; ++r) {
      float ar = __shfl(alpha, quad * 4 + r, 16);
#pragma unroll
      for (int j = 0; j < 4; ++j) o[j][r] *= ar;
    }
    __threadfence_block();  // per-wave LDS RAW: order + lgkmcnt, no barrier

    bf16x8 pf0 = *(const bf16x8*)&pls[wv][l16 * 72 + quad * 8];
    bf16x8 pf1 = *(const bf16x8*)&pls[wv][l16 * 72 + 32 + quad * 8];
#pragma unroll
    for (int j = 0; j < 4; ++j) {
      bf16x8 vf0 = *(const bf16x8*)&vbuf[cur][(j * 16 + l16) * 64 + quad * 8];
      bf16x8 vf1 = *(const bf16x8*)&vbuf[cur][(j * 16 + l16) * 64 + 32 + quad * 8];
      o[j] = __builtin_amdgcn_mfma_f32_16x16x32_bf16(pf0, vf0, o[j], 0, 0, 0);
      o[j] = __builtin_amdgcn_mfma_f32_16x16x32_bf16(pf1, vf1, o[j], 0, 0, 0);
    }
  }
#undef STAGE
  // Normalize + write O[q][h*64+d];  l for row quad*4+r fetched cross-lane.
#pragma unroll
  for (int r = 0; r < 4; ++r) {
    float lr = __shfl(l_l, quad * 4 + r, 16);
    float inv = 1.0f / lr;
    int row = qstrip + quad * 4 + r;
#pragma unroll
    for (int j = 0; j < 4; ++j)
      O[(bT + row) * EMB + h * 64 + j * 16 + l16] = f2bf(o[j][r] * inv);
  }
}

extern "C" void kernel_launch(void* const* d_in, const int* in_sizes, int n_in,
                              void* d_out, int out_size, void* d_ws, size_t ws_size,
                              hipStream_t stream) {
  const float* x  = (const float*)d_in[0];
  const float* Wq = (const float*)d_in[1];
  const float* Wk = (const float*)d_in[2];
  const float* Wv = (const float*)d_in[3];
  const float* Wp = (const float*)d_in[4];
  const float* bp = (const float*)d_in[5];
  float* out = (float*)d_out;

  u16* ws = (u16*)d_ws;
  u16* Qb  = ws;                              // 8M u16
  u16* Kb  = Qb + (size_t)8192 * 1024;        // 2M
  u16* Vb  = Kb + (size_t)8192 * 256;         // 2M
  u16* Vtb = Vb + (size_t)8192 * 256;         // 2M
  u16* xb  = Vtb + (size_t)8192 * 256;        // 8M (reused as Ab after QKV)
  u16* Wqb = xb + (size_t)8192 * 1024;        // 1M
  u16* Wkb = Wqb + (size_t)1024 * 1024;       // 256K
  u16* Wvb = Wkb + (size_t)256 * 1024;        // 256K
  u16* Wpb = Wvb + (size_t)256 * 1024;        // 1M  -> 24.5M u16 = 49 MB
  u16* Ab  = xb;                              // alias: x dead after QKV GEMMs

  f32_to_bf16<<<dim3(8192 * 1024 / 2048), 256, 0, stream>>>(x,  xb,  8192 * 1024);
  f32_to_bf16<<<dim3(1024 * 1024 / 2048), 256, 0, stream>>>(Wq, Wqb, 1024 * 1024);
  f32_to_bf16<<<dim3(256 * 1024 / 2048),  256, 0, stream>>>(Wk, Wkb, 256 * 1024);
  f32_to_bf16<<<dim3(256 * 1024 / 2048),  256, 0, stream>>>(Wv, Wvb, 256 * 1024);
  f32_to_bf16<<<dim3(1024 * 1024 / 2048), 256, 0, stream>>>(Wp, Wpb, 1024 * 1024);

  gemm_bt<false><<<dim3(64, 8), 256, 0, stream>>>(xb, Wqb, nullptr, Qb, 8192, 1024, 1024);
  gemm_bt<false><<<dim3(64, 2), 256, 0, stream>>>(xb, Wkb, nullptr, Kb, 8192, 256, 1024);
  gemm_bt<false><<<dim3(64, 2), 256, 0, stream>>>(xb, Wvb, nullptr, Vb, 8192, 256, 1024);

  transpose_v<<<dim3(32, 4, 4), 256, 0, stream>>>(Vb, Vtb);

  gqa_attn<<<dim3(32, 16, 4), 256, 0, stream>>>(Qb, Kb, Vtb, Ab);

  gemm_bt<true><<<dim3(64, 8), 256, 0, stream>>>(Ab, Wpb, bp, out, 8192, 1024, 1024);
}

// Round 8
// 325.215 us; speedup vs baseline: 2.1909x; 1.3089x over previous
//
#include <hip/hip_runtime.h>

typedef unsigned short u16;
typedef __bf16 bf16_t;
typedef bf16_t bf16x8 __attribute__((ext_vector_type(8)));
typedef float f32x4 __attribute__((ext_vector_type(4)));
typedef u16 u16x8 __attribute__((ext_vector_type(8)));

#define T_SZ 2048
#define EMB 1024

static __device__ __forceinline__ u16 f2bf(float f) {
  union { float f; unsigned u; } v; v.f = f;
  return (u16)((v.u + 0x7fffu + ((v.u >> 16) & 1u)) >> 16);  // RNE
}
static __device__ __forceinline__ void async16(const u16* g, u16* l) {
  typedef const __attribute__((address_space(1))) unsigned int* gp_t;
  typedef __attribute__((address_space(3))) unsigned int* lp_t;
  // LDS dest = wave-uniform base + lane*16.  Per-lane (even permuted) global
  // source addresses verified correct by the R4<->R7 absmax-identity oracle.
  __builtin_amdgcn_global_load_lds((gp_t)(const void*)g, (lp_t)(void*)l, 16, 0, 0);
}

// One fused fp32->bf16 convert for all 5 tensors (proven: R6≡R7 oracle).
__global__ __launch_bounds__(256) void cvt_all(
    const float* __restrict__ x,  const float* __restrict__ Wq,
    const float* __restrict__ Wk, const float* __restrict__ Wv,
    const float* __restrict__ Wp, u16* __restrict__ xb, u16* __restrict__ Wqb,
    u16* __restrict__ Wkb, u16* __restrict__ Wvb, u16* __restrict__ Wpb) {
  int bid = blockIdx.x;
  const float* src; u16* dst; int off;
  if (bid < 4096)      { src = x;  dst = xb;  off = bid * 2048; }
  else if (bid < 4608) { src = Wq; dst = Wqb; off = (bid - 4096) * 2048; }
  else if (bid < 4736) { src = Wk; dst = Wkb; off = (bid - 4608) * 2048; }
  else if (bid < 4864) { src = Wv; dst = Wvb; off = (bid - 4736) * 2048; }
  else                 { src = Wp; dst = Wpb; off = (bid - 4864) * 2048; }
  int i = off + threadIdx.x * 8;
  float4 a = *(const float4*)(src + i);
  float4 b = *(const float4*)(src + i + 4);
  u16x8 o;
  o[0] = f2bf(a.x); o[1] = f2bf(a.y); o[2] = f2bf(a.z); o[3] = f2bf(a.w);
  o[4] = f2bf(b.x); o[5] = f2bf(b.y); o[6] = f2bf(b.z); o[7] = f2bf(b.w);
  *(u16x8*)(dst + i) = o;
}

// V [b*T][g*64+d] -> Vt [(b*4+g)*64+d][T].  (R3-verbatim, proven)
__global__ __launch_bounds__(256) void transpose_v(
    const u16* __restrict__ V, u16* __restrict__ Vt) {
  __shared__ u16 tile[64][72];
  const int tt = blockIdx.x, g = blockIdx.y, b = blockIdx.z;
  const int tid = threadIdx.x;
  {
    const int r = tid >> 2, c = (tid & 3) * 16;
    const u16* src = V + ((size_t)(b * T_SZ + tt * 64 + r)) * 256 + g * 64 + c;
    *(u16x8*)&tile[r][c] = *(const u16x8*)src;
    *(u16x8*)&tile[r][c + 8] = *(const u16x8*)(src + 8);
  }
  __syncthreads();
  {
    const int d = tid >> 2, t0 = (tid & 3) * 16;
    u16x8 o0, o1;
#pragma unroll
    for (int i = 0; i < 8; ++i) { o0[i] = tile[t0 + i][d]; o1[i] = tile[t0 + 8 + i][d]; }
    u16* dst = Vt + ((size_t)((b * 4 + g) * 64 + d)) * T_SZ + tt * 64 + t0;
    *(u16x8*)dst = o0;
    *(u16x8*)(dst + 8) = o1;
  }
}

// GEMM body with XOR-swizzled gather staging (proven: R4≡R7 oracle).
// LDS slot (row, chunk) holds logical chunk chunk^(row&7); reads invert it.
template <bool OUT_F32>
__device__ __forceinline__ void gemm_body(
    const u16* __restrict__ A, const u16* __restrict__ Bm,
    const float* __restrict__ bias, void* __restrict__ Cv,
    int N, int K, int tm, int tn) {
  __shared__ u16 as[128 * 64];
  __shared__ u16 bs[128 * 64];
  const int tid = threadIdx.x;
  const int lane = tid & 63, wv = tid >> 6;
  const int quad = lane >> 4, l16 = lane & 15;
  const int wm = (wv & 1) * 64, wn = (wv >> 1) * 64;
  const int rA = lane >> 3;
  const int cS = ((lane & 7) ^ (rA & 7)) * 8;  // swizzled source chunk offset
  const int x7 = l16 & 7;
  f32x4 acc[4][4] = {};
  for (int k0 = 0; k0 < K; k0 += 64) {
#pragma unroll
    for (int it = 0; it < 4; ++it) {
      int r0 = it * 32 + wv * 8;
      async16(A + (size_t)(tm + r0 + rA) * K + k0 + cS, &as[r0 * 64]);
      async16(Bm + (size_t)(tn + r0 + rA) * K + k0 + cS, &bs[r0 * 64]);
    }
    __syncthreads();
#pragma unroll
    for (int kk = 0; kk < 64; kk += 32) {
      const int cb = kk >> 3;  // logical chunk base (0 or 4)
      bf16x8 af[4], bfr[4];
#pragma unroll
      for (int i = 0; i < 4; ++i)
        af[i] = *(const bf16x8*)&as[(wm + i * 16 + l16) * 64 + (((cb + quad) ^ x7) * 8)];
#pragma unroll
      for (int j = 0; j < 4; ++j)
        bfr[j] = *(const bf16x8*)&bs[(wn + j * 16 + l16) * 64 + (((cb + quad) ^ x7) * 8)];
#pragma unroll
      for (int i = 0; i < 4; ++i)
#pragma unroll
        for (int j = 0; j < 4; ++j)
          acc[i][j] = __builtin_amdgcn_mfma_f32_16x16x32_bf16(af[i], bfr[j], acc[i][j], 0, 0, 0);
    }
    __syncthreads();
  }
#pragma unroll
  for (int i = 0; i < 4; ++i)
#pragma unroll
    for (int j = 0; j < 4; ++j) {
      int col = tn + wn + j * 16 + l16;
      float bv = bias ? bias[col] : 0.0f;
#pragma unroll
      for (int r = 0; r < 4; ++r) {
        int row = tm + wm + i * 16 + quad * 4 + r;
        if (OUT_F32)
          ((float*)Cv)[(size_t)row * N + col] = acc[i][j][r] + bv;
        else
          ((u16*)Cv)[(size_t)row * N + col] = f2bf(acc[i][j][r] + bv);
      }
    }
}

// Fused Q/K/V projection: one launch, grid (64, 12).  (proven: R6≡R7 oracle)
__global__ __launch_bounds__(256, 2) void gemm_qkv(
    const u16* __restrict__ x, const u16* __restrict__ Wq,
    const u16* __restrict__ Wk, const u16* __restrict__ Wv,
    u16* __restrict__ Qb, u16* __restrict__ Kb, u16* __restrict__ Vb) {
  const int y = blockIdx.y;
  const u16* Bm; u16* C; int N, tn;
  if (y < 8)       { Bm = Wq; C = Qb; N = 1024; tn = y * 128; }
  else if (y < 10) { Bm = Wk; C = Kb; N = 256;  tn = (y - 8) * 128; }
  else             { Bm = Wv; C = Vb; N = 256;  tn = (y - 10) * 128; }
  gemm_body<false>(x, Bm, nullptr, C, N, 1024, blockIdx.x * 128, tn);
}

// Output projection, fp32 out + bias.
__global__ __launch_bounds__(256, 2) void gemm_out(
    const u16* __restrict__ A, const u16* __restrict__ Wp,
    const float* __restrict__ bias, float* __restrict__ C) {
  gemm_body<true>(A, Wp, bias, C, 1024, 1024, blockIdx.x * 128, blockIdx.y * 128);
}

// Flash attention, causal, GQA — SINGLE-strip (R3 structure, dual-strip removed
// after R4-R7 bisection convicted it) + swizzled gather staging and swizzled
// fragment reads (both proven by the absmax-identity oracle).
// Q:[B*T][1024] (h*64+d), K:[B*T][256] (g*64+d), Vt:[(b*4+g)*64+d][T].
__global__ __launch_bounds__(256, 3) void gqa_attn(
    const u16* __restrict__ Q, const u16* __restrict__ Kg,
    const u16* __restrict__ Vt, u16* __restrict__ O) {
  __shared__ u16 kbuf[2][64 * 64];   // K-tile [kpos][d], swizzled
  __shared__ u16 vbuf[2][64 * 64];   // V^T-tile [d][kpos], swizzled
  __shared__ u16 pls[4][16 * 72];    // per-wave P [q][kpos], stride 72
  const int tid = threadIdx.x;
  const int lane = tid & 63, wv = tid >> 6;
  const int quad = lane >> 4, l16 = lane & 15;
  const int qb = (int)(gridDim.x - 1) - (int)blockIdx.x;  // heaviest first
  const int h = blockIdx.y, b = blockIdx.z, g = h >> 2;
  const size_t bT = (size_t)b * T_SZ;
  const int qstrip = qb * 64 + wv * 16;
  const int rA = lane >> 3;
  const int cS = ((lane & 7) ^ (rA & 7)) * 8;  // swizzled source chunk offset
  const int x7 = l16 & 7;
  const u16* vtb = Vt + (size_t)((b * 4 + g) * 64) * T_SZ;

  // Q B-fragment (n = q = l16, k = quad*8+j), held for the whole loop.
  const u16* qp = Q + (bT + qstrip + l16) * EMB + h * 64 + quad * 8;
  const bf16x8 qf0 = *(const bf16x8*)qp;
  const bf16x8 qf1 = *(const bf16x8*)(qp + 32);

  f32x4 o[4] = {};                 // O^C: [q=quad*4+r][d=j*16+l16]
  float m_l = -1e30f, l_l = 0.0f;  // per-lane running max/sum for q = qstrip+l16
  const float SCALE2 = 0.18033688011112042f;  // 0.125 * log2(e)

#define STAGE(KT, BUF)                                                              \
  do {                                                                              \
    int kb_ = (KT) * 64, r0_ = wv * 16;                                             \
    async16(Kg + (bT + kb_ + r0_ + rA) * 256 + g * 64 + cS, &kbuf[BUF][r0_ * 64]);  \
    async16(Kg + (bT + kb_ + r0_ + 8 + rA) * 256 + g * 64 + cS,                     \
            &kbuf[BUF][(r0_ + 8) * 64]);                                            \
    async16(vtb + (size_t)(r0_ + rA) * T_SZ + kb_ + cS, &vbuf[BUF][r0_ * 64]);      \
    async16(vtb + (size_t)(r0_ + 8 + rA) * T_SZ + kb_ + cS,                         \
            &vbuf[BUF][(r0_ + 8) * 64]);                                            \
  } while (0)

  STAGE(0, 0);
  for (int kt = 0; kt <= qb; ++kt) {
    const int cur = kt & 1;
    __syncthreads();                 // drains stage(kt), prefetched last iter
    if (kt < qb) STAGE(kt + 1, cur ^ 1);

    // S^T = K Q^T : s[jn][r] = S[kpos = kt*64+jn*16+quad*4+r][q = qstrip+l16]
    f32x4 s[4];
#pragma unroll
    for (int jn = 0; jn < 4; ++jn) {
      const int rowb = (jn * 16 + l16) * 64;
      bf16x8 kf0 = *(const bf16x8*)&kbuf[cur][rowb + ((quad ^ x7) * 8)];
      bf16x8 kf1 = *(const bf16x8*)&kbuf[cur][rowb + (((4 + quad) ^ x7) * 8)];
      f32x4 a = {};
      a = __builtin_amdgcn_mfma_f32_16x16x32_bf16(kf0, qf0, a, 0, 0, 0);
      a = __builtin_amdgcn_mfma_f32_16x16x32_bf16(kf1, qf1, a, 0, 0, 0);
      s[jn] = a;
    }
    const int qg = qstrip + l16, kb = kt * 64;
#pragma unroll
    for (int jn = 0; jn < 4; ++jn)
#pragma unroll
      for (int r = 0; r < 4; ++r) {
        float v = s[jn][r] * SCALE2;               // log2 domain
        if (kb + jn * 16 + quad * 4 + r > qg) v = -1e30f;
        s[jn][r] = v;
      }

    // Online softmax: one q-row per lane; intra-lane 16-max, then xor16/xor32.
    float mx = -1e30f;
#pragma unroll
    for (int jn = 0; jn < 4; ++jn)
#pragma unroll
      for (int r = 0; r < 4; ++r) mx = fmaxf(mx, s[jn][r]);
    mx = fmaxf(mx, __shfl_xor(mx, 16));
    mx = fmaxf(mx, __shfl_xor(mx, 32));
    float mnew = fmaxf(m_l, mx);
    float alpha = exp2f(m_l - mnew);
    float sum = 0.0f;
#pragma unroll
    for (int jn = 0; jn < 4; ++jn)
#pragma unroll
      for (int r = 0; r < 4; ++r) { s[jn][r] = exp2f(s[jn][r] - mnew); sum += s[jn][r]; }
    sum += __shfl_xor(sum, 16);
    sum += __shfl_xor(sum, 32);
    l_l = l_l * alpha + sum;
    m_l = mnew;

    // P store: 4 consecutive kpos per lane -> ds_write_b64 into stride-72 rows.
#pragma unroll
    for (int jn = 0; jn < 4; ++jn) {
      ushort4 pk;
      pk.x = f2bf(s[jn][0]); pk.y = f2bf(s[jn][1]);
      pk.z = f2bf(s[jn][2]); pk.w = f2bf(s[jn][3]);
      *(ushort4*)&pls[wv][l16 * 72 + jn * 16 + quad * 4] = pk;
    }
    // Rescale O by alpha[row q = quad*4+r] (fetched cross-lane).
#pragma unroll
    for (int r = 0; r < 4; ++r) {
      float ar = __shfl(alpha, quad * 4 + r, 16);
#pragma unroll
      for (int j = 0; j < 4; ++j) o[j][r] *= ar;
    }
    __syncthreads();  // P u16->bf16 round-trip: full compiler+HW ordering

    bf16x8 pf0 = *(const bf16x8*)&pls[wv][l16 * 72 + quad * 8];
    bf16x8 pf1 = *(const bf16x8*)&pls[wv][l16 * 72 + 32 + quad * 8];
#pragma unroll
    for (int j = 0; j < 4; ++j) {
      const int rowb = (j * 16 + l16) * 64;
      bf16x8 vf0 = *(const bf16x8*)&vbuf[cur][rowb + ((quad ^ x7) * 8)];
      bf16x8 vf1 = *(const bf16x8*)&vbuf[cur][rowb + (((4 + quad) ^ x7) * 8)];
      o[j] = __builtin_amdgcn_mfma_f32_16x16x32_bf16(pf0, vf0, o[j], 0, 0, 0);
      o[j] = __builtin_amdgcn_mfma_f32_16x16x32_bf16(pf1, vf1, o[j], 0, 0, 0);
    }
  }
#undef STAGE
  // Normalize + write O[b*T+q][h*64+d].
#pragma unroll
  for (int r = 0; r < 4; ++r) {
    float inv = 1.0f / __shfl(l_l, quad * 4 + r, 16);
    int row = qstrip + quad * 4 + r;
#pragma unroll
    for (int j = 0; j < 4; ++j)
      O[(bT + row) * EMB + h * 64 + j * 16 + l16] = f2bf(o[j][r] * inv);
  }
}

extern "C" void kernel_launch(void* const* d_in, const int* in_sizes, int n_in,
                              void* d_out, int out_size, void* d_ws, size_t ws_size,
                              hipStream_t stream) {
  const float* x  = (const float*)d_in[0];
  const float* Wq = (const float*)d_in[1];
  const float* Wk = (const float*)d_in[2];
  const float* Wv = (const float*)d_in[3];
  const float* Wp = (const float*)d_in[4];
  const float* bp = (const float*)d_in[5];
  float* out = (float*)d_out;

  u16* ws = (u16*)d_ws;
  u16* Qb  = ws;                              // 8M u16
  u16* Kb  = Qb + (size_t)8192 * 1024;        // 2M
  u16* Vb  = Kb + (size_t)8192 * 256;         // 2M
  u16* Vtb = Vb + (size_t)8192 * 256;         // 2M
  u16* xb  = Vtb + (size_t)8192 * 256;        // 8M (reused as Ab after QKV)
  u16* Wqb = xb + (size_t)8192 * 1024;        // 1M
  u16* Wkb = Wqb + (size_t)1024 * 1024;       // 256K
  u16* Wvb = Wkb + (size_t)256 * 1024;        // 256K
  u16* Wpb = Wvb + (size_t)256 * 1024;        // 1M  -> 24.5M u16 = 49 MB
  u16* Ab  = xb;                              // alias: x dead after QKV GEMM

  cvt_all<<<dim3(5376), 256, 0, stream>>>(x, Wq, Wk, Wv, Wp, xb, Wqb, Wkb, Wvb, Wpb);
  gemm_qkv<<<dim3(64, 12), 256, 0, stream>>>(xb, Wqb, Wkb, Wvb, Qb, Kb, Vb);
  transpose_v<<<dim3(32, 4, 4), 256, 0, stream>>>(Vb, Vtb);
  gqa_attn<<<dim3(32, 16, 4), 256, 0, stream>>>(Qb, Kb, Vtb, Ab);
  gemm_out<<<dim3(64, 8), 256, 0, stream>>>(Ab, Wpb, bp, out);
}

// Round 9
// 295.301 us; speedup vs baseline: 2.4128x; 1.1013x over previous
//
#include <hip/hip_runtime.h>

typedef unsigned short u16;
typedef __bf16 bf16_t;
typedef bf16_t bf16x8 __attribute__((ext_vector_type(8)));
typedef float f32x4 __attribute__((ext_vector_type(4)));
typedef u16 u16x8 __attribute__((ext_vector_type(8)));

#define T_SZ 2048
#define EMB 1024

static __device__ __forceinline__ u16 f2bf(float f) {
  union { float f; unsigned u; } v; v.f = f;
  return (u16)((v.u + 0x7fffu + ((v.u >> 16) & 1u)) >> 16);  // RNE
}
static __device__ __forceinline__ void async16(const u16* g, u16* l) {
  typedef const __attribute__((address_space(1))) unsigned int* gp_t;
  typedef __attribute__((address_space(3))) unsigned int* lp_t;
  // LDS dest = wave-uniform base + lane*16.  Per-lane (even permuted) global
  // source addresses proven correct by the R4<->R7 absmax-identity oracle.
  __builtin_amdgcn_global_load_lds((gp_t)(const void*)g, (lp_t)(void*)l, 16, 0, 0);
}

// One fused fp32->bf16 convert for all 5 tensors (proven R6/R8).
__global__ __launch_bounds__(256) void cvt_all(
    const float* __restrict__ x,  const float* __restrict__ Wq,
    const float* __restrict__ Wk, const float* __restrict__ Wv,
    const float* __restrict__ Wp, u16* __restrict__ xb, u16* __restrict__ Wqb,
    u16* __restrict__ Wkb, u16* __restrict__ Wvb, u16* __restrict__ Wpb) {
  int bid = blockIdx.x;
  const float* src; u16* dst; int off;
  if (bid < 4096)      { src = x;  dst = xb;  off = bid * 2048; }
  else if (bid < 4608) { src = Wq; dst = Wqb; off = (bid - 4096) * 2048; }
  else if (bid < 4736) { src = Wk; dst = Wkb; off = (bid - 4608) * 2048; }
  else if (bid < 4864) { src = Wv; dst = Wvb; off = (bid - 4736) * 2048; }
  else                 { src = Wp; dst = Wpb; off = (bid - 4864) * 2048; }
  int i = off + threadIdx.x * 8;
  float4 a = *(const float4*)(src + i);
  float4 b = *(const float4*)(src + i + 4);
  u16x8 o;
  o[0] = f2bf(a.x); o[1] = f2bf(a.y); o[2] = f2bf(a.z); o[3] = f2bf(a.w);
  o[4] = f2bf(b.x); o[5] = f2bf(b.y); o[6] = f2bf(b.z); o[7] = f2bf(b.w);
  *(u16x8*)(dst + i) = o;
}

// V [b*T][g*64+d] -> Vt [(b*4+g)*64+d][T].  (proven)
__global__ __launch_bounds__(256) void transpose_v(
    const u16* __restrict__ V, u16* __restrict__ Vt) {
  __shared__ u16 tile[64][72];
  const int tt = blockIdx.x, g = blockIdx.y, b = blockIdx.z;
  const int tid = threadIdx.x;
  {
    const int r = tid >> 2, c = (tid & 3) * 16;
    const u16* src = V + ((size_t)(b * T_SZ + tt * 64 + r)) * 256 + g * 64 + c;
    *(u16x8*)&tile[r][c] = *(const u16x8*)src;
    *(u16x8*)&tile[r][c + 8] = *(const u16x8*)(src + 8);
  }
  __syncthreads();
  {
    const int d = tid >> 2, t0 = (tid & 3) * 16;
    u16x8 o0, o1;
#pragma unroll
    for (int i = 0; i < 8; ++i) { o0[i] = tile[t0 + i][d]; o1[i] = tile[t0 + 8 + i][d]; }
    u16* dst = Vt + ((size_t)((b * 4 + g) * 64 + d)) * T_SZ + tt * 64 + t0;
    *(u16x8*)dst = o0;
    *(u16x8*)(dst + 8) = o1;
  }
}

// GEMM body with XOR-swizzled gather staging (proven R8).
template <bool OUT_F32>
__device__ __forceinline__ void gemm_body(
    const u16* __restrict__ A, const u16* __restrict__ Bm,
    const float* __restrict__ bias, void* __restrict__ Cv,
    int N, int K, int tm, int tn) {
  __shared__ u16 as[128 * 64];
  __shared__ u16 bs[128 * 64];
  const int tid = threadIdx.x;
  const int lane = tid & 63, wv = tid >> 6;
  const int quad = lane >> 4, l16 = lane & 15;
  const int wm = (wv & 1) * 64, wn = (wv >> 1) * 64;
  const int rA = lane >> 3;
  const int cS = ((lane & 7) ^ (rA & 7)) * 8;
  const int x7 = l16 & 7;
  f32x4 acc[4][4] = {};
  for (int k0 = 0; k0 < K; k0 += 64) {
#pragma unroll
    for (int it = 0; it < 4; ++it) {
      int r0 = it * 32 + wv * 8;
      async16(A + (size_t)(tm + r0 + rA) * K + k0 + cS, &as[r0 * 64]);
      async16(Bm + (size_t)(tn + r0 + rA) * K + k0 + cS, &bs[r0 * 64]);
    }
    __syncthreads();
#pragma unroll
    for (int kk = 0; kk < 64; kk += 32) {
      const int cb = kk >> 3;
      bf16x8 af[4], bfr[4];
#pragma unroll
      for (int i = 0; i < 4; ++i)
        af[i] = *(const bf16x8*)&as[(wm + i * 16 + l16) * 64 + (((cb + quad) ^ x7) * 8)];
#pragma unroll
      for (int j = 0; j < 4; ++j)
        bfr[j] = *(const bf16x8*)&bs[(wn + j * 16 + l16) * 64 + (((cb + quad) ^ x7) * 8)];
#pragma unroll
      for (int i = 0; i < 4; ++i)
#pragma unroll
        for (int j = 0; j < 4; ++j)
          acc[i][j] = __builtin_amdgcn_mfma_f32_16x16x32_bf16(af[i], bfr[j], acc[i][j], 0, 0, 0);
    }
    __syncthreads();
  }
#pragma unroll
  for (int i = 0; i < 4; ++i)
#pragma unroll
    for (int j = 0; j < 4; ++j) {
      int col = tn + wn + j * 16 + l16;
      float bv = bias ? bias[col] : 0.0f;
#pragma unroll
      for (int r = 0; r < 4; ++r) {
        int row = tm + wm + i * 16 + quad * 4 + r;
        if (OUT_F32)
          ((float*)Cv)[(size_t)row * N + col] = acc[i][j][r] + bv;
        else
          ((u16*)Cv)[(size_t)row * N + col] = f2bf(acc[i][j][r] + bv);
      }
    }
}

// Fused Q/K/V projection (proven R8).
__global__ __launch_bounds__(256, 2) void gemm_qkv(
    const u16* __restrict__ x, const u16* __restrict__ Wq,
    const u16* __restrict__ Wk, const u16* __restrict__ Wv,
    u16* __restrict__ Qb, u16* __restrict__ Kb, u16* __restrict__ Vb) {
  const int y = blockIdx.y;
  const u16* Bm; u16* C; int N, tn;
  if (y < 8)       { Bm = Wq; C = Qb; N = 1024; tn = y * 128; }
  else if (y < 10) { Bm = Wk; C = Kb; N = 256;  tn = (y - 8) * 128; }
  else             { Bm = Wv; C = Vb; N = 256;  tn = (y - 10) * 128; }
  gemm_body<false>(x, Bm, nullptr, C, N, 1024, blockIdx.x * 128, tn);
}

// Output projection, fp32 out + bias (proven R8).
__global__ __launch_bounds__(256, 2) void gemm_out(
    const u16* __restrict__ A, const u16* __restrict__ Wp,
    const float* __restrict__ bias, float* __restrict__ C) {
  gemm_body<true>(A, Wp, bias, C, 1024, 1024, blockIdx.x * 128, blockIdx.y * 128);
}

// Flash attention, causal, GQA — R8's proven per-wave single-strip body, now
// 8 waves/block covering 128 q rows of one head; all waves share the staged
// K/V tiles (staging per q-row halved, occupancy cap 12->24 waves/CU).
// Wave wv owns q rows qstrip..qstrip+15, qstrip = qt*128 + wv*16.  Inactive
// waves (kb > qstrip+15: waves 0-3 on the final tile only) skip compute but
// hit both barriers (block-uniform nkt).
__global__ __launch_bounds__(512, 6) void gqa_attn(
    const u16* __restrict__ Q, const u16* __restrict__ Kg,
    const u16* __restrict__ Vt, u16* __restrict__ O) {
  __shared__ u16 kbuf[2][64 * 64];   // K-tile [kpos][d], swizzled
  __shared__ u16 vbuf[2][64 * 64];   // V^T-tile [d][kpos], swizzled
  __shared__ u16 pls[8][16 * 72];    // per-wave P [q][kpos], stride 72
  const int tid = threadIdx.x;
  const int lane = tid & 63, wv = tid >> 6;
  const int quad = lane >> 4, l16 = lane & 15;
  const int qt = 15 - (int)blockIdx.x;  // heaviest first
  const int h = blockIdx.y, b = blockIdx.z, g = h >> 2;
  const size_t bT = (size_t)b * T_SZ;
  const int qstrip = qt * 128 + wv * 16;
  const int rA = lane >> 3;
  const int cS = ((lane & 7) ^ (rA & 7)) * 8;  // swizzled source chunk offset
  const int x7 = l16 & 7;
  const u16* vtb = Vt + (size_t)((b * 4 + g) * 64) * T_SZ;
  const int nkt = 2 * qt + 2;

  // Q B-fragment (n = q = l16, k = quad*8+j), held for the whole loop.
  const u16* qp = Q + (bT + qstrip + l16) * EMB + h * 64 + quad * 8;
  const bf16x8 qf0 = *(const bf16x8*)qp;
  const bf16x8 qf1 = *(const bf16x8*)(qp + 32);

  f32x4 o[4] = {};                 // O^C: [q=quad*4+r][d=j*16+l16]
  float m_l = -1e30f, l_l = 0.0f;  // per-lane running max/sum for q = qstrip+l16
  const float SCALE2 = 0.18033688011112042f;  // 0.125 * log2(e)

#define STAGE(KT, BUF)                                                              \
  do {                                                                              \
    int kb_ = (KT) * 64, r0_ = wv * 8;  /* 8 waves x 8 rows = 64 */                 \
    async16(Kg + (bT + kb_ + r0_ + rA) * 256 + g * 64 + cS, &kbuf[BUF][r0_ * 64]);  \
    async16(vtb + (size_t)(r0_ + rA) * T_SZ + kb_ + cS, &vbuf[BUF][r0_ * 64]);      \
  } while (0)

  STAGE(0, 0);
  for (int kt = 0; kt < nkt; ++kt) {
    const int cur = kt & 1;
    __syncthreads();                 // drains stage(kt), prefetched last iter
    if (kt + 1 < nkt) STAGE(kt + 1, cur ^ 1);
    const int kb = kt * 64;
    const bool act = (kb <= qstrip + 15);  // wave-uniform

    f32x4 s[4];
    float alpha;
    if (act) {
      // S^T = K Q^T : s[jn][r] = S[kpos = kt*64+jn*16+quad*4+r][q = qstrip+l16]
#pragma unroll
      for (int jn = 0; jn < 4; ++jn) {
        const int rowb = (jn * 16 + l16) * 64;
        bf16x8 kf0 = *(const bf16x8*)&kbuf[cur][rowb + ((quad ^ x7) * 8)];
        bf16x8 kf1 = *(const bf16x8*)&kbuf[cur][rowb + (((4 + quad) ^ x7) * 8)];
        f32x4 a = {};
        a = __builtin_amdgcn_mfma_f32_16x16x32_bf16(kf0, qf0, a, 0, 0, 0);
        a = __builtin_amdgcn_mfma_f32_16x16x32_bf16(kf1, qf1, a, 0, 0, 0);
        s[jn] = a;
      }
      const int qg = qstrip + l16;
#pragma unroll
      for (int jn = 0; jn < 4; ++jn)
#pragma unroll
        for (int r = 0; r < 4; ++r) {
          float v = s[jn][r] * SCALE2;               // log2 domain
          if (kb + jn * 16 + quad * 4 + r > qg) v = -1e30f;
          s[jn][r] = v;
        }

      // Online softmax: one q-row per lane; intra-lane 16-max, then xor16/32.
      float mx = -1e30f;
#pragma unroll
      for (int jn = 0; jn < 4; ++jn)
#pragma unroll
        for (int r = 0; r < 4; ++r) mx = fmaxf(mx, s[jn][r]);
      mx = fmaxf(mx, __shfl_xor(mx, 16));
      mx = fmaxf(mx, __shfl_xor(mx, 32));
      float mnew = fmaxf(m_l, mx);
      alpha = exp2f(m_l - mnew);
      float sum = 0.0f;
#pragma unroll
      for (int jn = 0; jn < 4; ++jn)
#pragma unroll
        for (int r = 0; r < 4; ++r) { s[jn][r] = exp2f(s[jn][r] - mnew); sum += s[jn][r]; }
      sum += __shfl_xor(sum, 16);
      sum += __shfl_xor(sum, 32);
      l_l = l_l * alpha + sum;
      m_l = mnew;

      // P store: 4 consecutive kpos per lane -> ds_write_b64, stride-72 rows.
#pragma unroll
      for (int jn = 0; jn < 4; ++jn) {
        ushort4 pk;
        pk.x = f2bf(s[jn][0]); pk.y = f2bf(s[jn][1]);
        pk.z = f2bf(s[jn][2]); pk.w = f2bf(s[jn][3]);
        *(ushort4*)&pls[wv][l16 * 72 + jn * 16 + quad * 4] = pk;
      }
      // Rescale O by alpha[row q = quad*4+r] (fetched cross-lane).
#pragma unroll
      for (int r = 0; r < 4; ++r) {
        float ar = __shfl(alpha, quad * 4 + r, 16);
#pragma unroll
        for (int j = 0; j < 4; ++j) o[j][r] *= ar;
      }
    }
    __syncthreads();  // P u16->bf16 round-trip ordering (block-uniform count)

    if (act) {
      bf16x8 pf0 = *(const bf16x8*)&pls[wv][l16 * 72 + quad * 8];
      bf16x8 pf1 = *(const bf16x8*)&pls[wv][l16 * 72 + 32 + quad * 8];
#pragma unroll
      for (int j = 0; j < 4; ++j) {
        const int rowb = (j * 16 + l16) * 64;
        bf16x8 vf0 = *(const bf16x8*)&vbuf[cur][rowb + ((quad ^ x7) * 8)];
        bf16x8 vf1 = *(const bf16x8*)&vbuf[cur][rowb + (((4 + quad) ^ x7) * 8)];
        o[j] = __builtin_amdgcn_mfma_f32_16x16x32_bf16(pf0, vf0, o[j], 0, 0, 0);
        o[j] = __builtin_amdgcn_mfma_f32_16x16x32_bf16(pf1, vf1, o[j], 0, 0, 0);
      }
    }
  }
#undef STAGE
  // Normalize + write O[b*T+q][h*64+d].
#pragma unroll
  for (int r = 0; r < 4; ++r) {
    float inv = 1.0f / __shfl(l_l, quad * 4 + r, 16);
    int row = qstrip + quad * 4 + r;
#pragma unroll
    for (int j = 0; j < 4; ++j)
      O[(bT + row) * EMB + h * 64 + j * 16 + l16] = f2bf(o[j][r] * inv);
  }
}

extern "C" void kernel_launch(void* const* d_in, const int* in_sizes, int n_in,
                              void* d_out, int out_size, void* d_ws, size_t ws_size,
                              hipStream_t stream) {
  const float* x  = (const float*)d_in[0];
  const float* Wq = (const float*)d_in[1];
  const float* Wk = (const float*)d_in[2];
  const float* Wv = (const float*)d_in[3];
  const float* Wp = (const float*)d_in[4];
  const float* bp = (const float*)d_in[5];
  float* out = (float*)d_out;

  u16* ws = (u16*)d_ws;
  u16* Qb  = ws;                              // 8M u16
  u16* Kb  = Qb + (size_t)8192 * 1024;        // 2M
  u16* Vb  = Kb + (size_t)8192 * 256;         // 2M
  u16* Vtb = Vb + (size_t)8192 * 256;         // 2M
  u16* xb  = Vtb + (size_t)8192 * 256;        // 8M (reused as Ab after QKV)
  u16* Wqb = xb + (size_t)8192 * 1024;        // 1M
  u16* Wkb = Wqb + (size_t)1024 * 1024;       // 256K
  u16* Wvb = Wkb + (size_t)256 * 1024;        // 256K
  u16* Wpb = Wvb + (size_t)256 * 1024;        // 1M  -> 24.5M u16 = 49 MB
  u16* Ab  = xb;                              // alias: x dead after QKV GEMM

  cvt_all<<<dim3(5376), 256, 0, stream>>>(x, Wq, Wk, Wv, Wp, xb, Wqb, Wkb, Wvb, Wpb);
  gemm_qkv<<<dim3(64, 12), 256, 0, stream>>>(xb, Wqb, Wkb, Wvb, Qb, Kb, Vb);
  transpose_v<<<dim3(32, 4, 4), 256, 0, stream>>>(Vb, Vtb);
  gqa_attn<<<dim3(16, 16, 4), 512, 0, stream>>>(Qb, Kb, Vtb, Ab);
  gemm_out<<<dim3(64, 8), 256, 0, stream>>>(Ab, Wpb, bp, out);
}